// Round 2
// baseline (286.727 us; speedup 1.0000x reference)
//
#include <hip/hip_runtime.h>

#define NTOK 4096          // N
#define EDIM 128

typedef __attribute__((ext_vector_type(8))) short bf16x8;
typedef __attribute__((ext_vector_type(4))) float f32x4;

__device__ __forceinline__ ushort f2bf(float x) {
    union { float f; unsigned u; } c; c.f = x;
    unsigned r = c.u + 0x7FFF + ((c.u >> 16) & 1);
    return (ushort)(r >> 16);
}

// XOR-swizzled LDS index helpers (ushort units). Row stride 64/128 ushorts;
// k ^= (row&7)<<3 spreads the 16-B chunks of 8 consecutive rows across banks
// (G4 recipe). Preserves 8-ushort (16 B) and 4-ushort (8 B) alignment.
__device__ __forceinline__ int swz64(int r, int k)  { return r * 64  + (k ^ ((r & 7) << 3)); }
__device__ __forceinline__ int swz128(int r, int k) { return r * 128 + (k ^ ((r & 7) << 3)); }

// stage a 128x128 fp32 weight (row-major) into bf16 LDS tile [128][136]
__device__ __forceinline__ void stage_w(const float* __restrict__ W, ushort* Bs) {
    const int t = threadIdx.x;
    const int br = t >> 1, h = (t & 1) * 64;
    const float* src = W + (size_t)br * 128 + h;
    ushort* dst = Bs + br * 136 + h;
#pragma unroll
    for (int j = 0; j < 8; ++j) {
        float4 u = *(const float4*)(src + j * 8);
        float4 v = *(const float4*)(src + j * 8 + 4);
        bf16x8 o;
        o[0] = (short)f2bf(u.x); o[1] = (short)f2bf(u.y);
        o[2] = (short)f2bf(u.z); o[3] = (short)f2bf(u.w);
        o[4] = (short)f2bf(v.x); o[5] = (short)f2bf(v.y);
        o[6] = (short)f2bf(v.z); o[7] = (short)f2bf(v.w);
        *(bf16x8*)(dst + j * 8) = o;
    }
}

// 32x128 x K=128 bf16 MFMA GEMM from LDS tiles (As[32][136], Bs[128][136])
__device__ __forceinline__ void gemm128(const ushort* __restrict__ As,
                                        const ushort* __restrict__ Bs,
                                        f32x4 (&acc)[2][2], int lane, int wv) {
    const int m15 = lane & 15, kq = (lane >> 4) * 8, c0w = wv * 32;
#pragma unroll
    for (int kc = 0; kc < 4; ++kc) {
        int ko = kc * 32 + kq;
        bf16x8 a0 = *(const bf16x8*)&As[m15 * 136 + ko];
        bf16x8 a1 = *(const bf16x8*)&As[(16 + m15) * 136 + ko];
        bf16x8 b0 = *(const bf16x8*)&Bs[(c0w + m15) * 136 + ko];
        bf16x8 b1 = *(const bf16x8*)&Bs[(c0w + 16 + m15) * 136 + ko];
        acc[0][0] = __builtin_amdgcn_mfma_f32_16x16x32_bf16(a0, b0, acc[0][0], 0, 0, 0);
        acc[0][1] = __builtin_amdgcn_mfma_f32_16x16x32_bf16(a0, b1, acc[0][1], 0, 0, 0);
        acc[1][0] = __builtin_amdgcn_mfma_f32_16x16x32_bf16(a1, b0, acc[1][0], 0, 0, 0);
        acc[1][1] = __builtin_amdgcn_mfma_f32_16x16x32_bf16(a1, b1, acc[1][1], 0, 0, 0);
    }
}

// 32x128 GEMM: A from swizzled LDS [32][128], B bf16 fragments DIRECT from
// global (per-wave-private rows -> no LDS staging, no barriers).
__device__ __forceinline__ void gemm_dirB(const ushort* __restrict__ As,
                                          const ushort* __restrict__ W, int ldb,
                                          f32x4 (&acc)[2][2], int lane, int wv) {
    const int m15 = lane & 15, kq = (lane >> 4) * 8, c0w = wv * 32;
#pragma unroll
    for (int kc = 0; kc < 4; ++kc) {
        int ko = kc * 32 + kq;
        bf16x8 a0 = *(const bf16x8*)&As[swz128(m15, ko)];
        bf16x8 a1 = *(const bf16x8*)&As[swz128(16 + m15, ko)];
        bf16x8 b0 = *(const bf16x8*)&W[(size_t)(c0w + m15) * ldb + ko];
        bf16x8 b1 = *(const bf16x8*)&W[(size_t)(c0w + 16 + m15) * ldb + ko];
        acc[0][0] = __builtin_amdgcn_mfma_f32_16x16x32_bf16(a0, b0, acc[0][0], 0, 0, 0);
        acc[0][1] = __builtin_amdgcn_mfma_f32_16x16x32_bf16(a0, b1, acc[0][1], 0, 0, 0);
        acc[1][0] = __builtin_amdgcn_mfma_f32_16x16x32_bf16(a1, b0, acc[1][0], 0, 0, 0);
        acc[1][1] = __builtin_amdgcn_mfma_f32_16x16x32_bf16(a1, b1, acc[1][1], 0, 0, 0);
    }
}

// ---------------------------------------------------------------------------
// K1: blocks [0,256): per-32-row fused rms1 + Q/K/V GEMMs -> sigq, Mt.
//     blocks [256,400): Wcomb/W1/W2 fp32->bf16 for the tail kernel.
// ---------------------------------------------------------------------------
__launch_bounds__(256, 2)
__global__ void qkv_k(const float* __restrict__ input1, const float* __restrict__ ln1w,
                      const float* __restrict__ Wq, const float* __restrict__ Wk,
                      const float* __restrict__ Wv,
                      const float* __restrict__ Wc, const float* __restrict__ W1,
                      const float* __restrict__ W2, ushort* __restrict__ Wbf,
                      float* __restrict__ sigq, ushort* __restrict__ Mt) {
    const int bx = blockIdx.x;
    if (bx >= 256) {                       // weight conversion (147456 f32)
        int g = ((bx - 256) * 256 + threadIdx.x) * 4;
        const float* src; ushort* dst;
        if (g < 16384)      { src = Wc + g;           dst = Wbf + 49152 + g; }
        else if (g < 81920) { src = W1 + (g - 16384); dst = Wbf + 65536 + (g - 16384); }
        else                { src = W2 + (g - 81920); dst = Wbf + 131072 + (g - 81920); }
        float4 u = *(const float4*)src;
        ushort4 o; o.x = f2bf(u.x); o.y = f2bf(u.y); o.z = f2bf(u.z); o.w = f2bf(u.w);
        *(ushort4*)dst = o;
        return;
    }
    __shared__ ushort As[32 * 136];
    __shared__ ushort Bs0[128 * 136];
    __shared__ ushort Bs1[128 * 136];
    const int t = threadIdx.x, lane = t & 63, wv = t >> 6;
    const int m15 = lane & 15, quad = lane >> 4, c0w = wv * 32;
    const int M0 = bx * 32;

    // rms1: h = rmsnorm(input1 rows, ln1) -> As (bf16)
    {
        const int row = t >> 3, seg = t & 7;
        const float* xp = input1 + (size_t)(M0 + row) * 128 + seg * 16;
        float4 x[4]; float ss = 0.f;
#pragma unroll
        for (int i = 0; i < 4; ++i) {
            x[i] = *(const float4*)(xp + i * 4);
            ss += x[i].x * x[i].x + x[i].y * x[i].y + x[i].z * x[i].z + x[i].w * x[i].w;
        }
        ss += __shfl_down(ss, 4, 8);
        ss += __shfl_down(ss, 2, 8);
        ss += __shfl_down(ss, 1, 8);
        ss = __shfl(ss, 0, 8);
        float rr = rsqrtf(ss * (1.0f / 128.0f) + 1e-6f);
#pragma unroll
        for (int i = 0; i < 4; ++i) {
            float4 w4 = *(const float4*)&ln1w[seg * 16 + i * 4];
            ushort4 o;
            o.x = f2bf(x[i].x * rr * w4.x);
            o.y = f2bf(x[i].y * rr * w4.y);
            o.z = f2bf(x[i].z * rr * w4.z);
            o.w = f2bf(x[i].w * rr * w4.w);
            *(ushort4*)&As[row * 136 + seg * 16 + i * 4] = o;
        }
    }
    stage_w(Wq, Bs0);
    __syncthreads();
    {   // GEMM q -> sigmoid -> sigq ; overlap Wk staging into Bs1
        f32x4 acc[2][2] = {};
        gemm128(As, Bs0, acc, lane, wv);
        stage_w(Wk, Bs1);
#pragma unroll
        for (int mi = 0; mi < 2; ++mi)
#pragma unroll
            for (int ni = 0; ni < 2; ++ni)
#pragma unroll
                for (int r = 0; r < 4; ++r) {
                    int row = M0 + mi * 16 + quad * 4 + r;
                    int lc  = c0w + ni * 16 + m15;
                    sigq[(size_t)row * 128 + lc] = 1.0f / (1.0f + __expf(-acc[mi][ni][r]));
                }
    }
    __syncthreads();
    f32x4 acck[2][2] = {};
    gemm128(As, Bs1, acck, lane, wv);
    stage_w(Wv, Bs0);                     // Bs0 free: all q-reads done at last barrier
    __syncthreads();
    f32x4 accv[2][2] = {};
    gemm128(As, Bs0, accv, lane, wv);
    // Mt epilogue: Mt[b][e][i]=exp(k)*v, Mt[b][128+e][i]=exp(k)
    const int b = M0 >> 12, i0 = M0 & (NTOK - 1);
#pragma unroll
    for (int mi = 0; mi < 2; ++mi)
#pragma unroll
        for (int ni = 0; ni < 2; ++ni) {
            int e = c0w + ni * 16 + m15;
            ushort* mt0 = Mt + ((size_t)b * 256 + e) * NTOK;
            ushort* mt1 = mt0 + (size_t)128 * NTOK;
            int ib = i0 + mi * 16 + quad * 4;
            ushort4 pv, pk;
            float kw0 = __expf(acck[mi][ni][0]); pv.x = f2bf(kw0 * accv[mi][ni][0]); pk.x = f2bf(kw0);
            float kw1 = __expf(acck[mi][ni][1]); pv.y = f2bf(kw1 * accv[mi][ni][1]); pk.y = f2bf(kw1);
            float kw2 = __expf(acck[mi][ni][2]); pv.z = f2bf(kw2 * accv[mi][ni][2]); pk.z = f2bf(kw2);
            float kw3 = __expf(acck[mi][ni][3]); pv.w = f2bf(kw3 * accv[mi][ni][3]); pk.w = f2bf(kw3);
            *(ushort4*)&mt0[ib] = pv;
            *(ushort4*)&mt1[ib] = pk;
        }
}

// ---------------------------------------------------------------------------
// K2: P[b,j,c] = sum_i exp(coef*dis[b,j,i]) * Mt[b,c,i]
// 32j x 256c tile, K-full (BK=64, 64 iters). Grid 256 = 128 j-tiles x 2 b;
// b = blockIdx&1 -> all blocks of one batch land on the same XCD parity, so
// each XCD L2 caches one 2 MB Mt panel. B (Mt) direct global->reg (no
// inter-wave reuse). A (dis) exp'd into XOR-swizzled LDS (conflict-free
// ds_read_b128). A prefetch depth 2 (HBM latency), B depth 1 (L2).
// ---------------------------------------------------------------------------
__launch_bounds__(512, 2)
__global__ void big_gemm_k(const float* __restrict__ dis, const float* __restrict__ alphap,
                           const ushort* __restrict__ Mt, float* __restrict__ P) {
    __shared__ ushort As[32 * 64];
    const int t = threadIdx.x, lane = t & 63, wv = t >> 6;
    const int m15 = lane & 15, quad = lane >> 4, kq = quad * 8;
    const int b  = blockIdx.x & 1;
    const int j0 = (blockIdx.x >> 1) * 32;
    const float coef = -alphap[0] * 12.0f;      // log2(4096) = 12
    const ushort* Mtb = Mt + (size_t)b * 256 * NTOK;
    float* outp = P + (size_t)b * NTOK * 256;

    const int sr = t >> 4, sk = (t & 15) * 4;   // staging: row, k-offset (ushorts)
    const float* arow = dis + (size_t)b * NTOK * NTOK + (size_t)(j0 + sr) * NTOK + sk;
    const int c0 = wv * 32;

    f32x4 acc[2][2] = {};
    float4 fa_e, fa_o;
    bf16x8 pb[2][2], pbn[2][2];
    fa_e = *(const float4*)(arow);              // iter 0
    fa_o = *(const float4*)(arow + 64);         // iter 1
#pragma unroll
    for (int kh = 0; kh < 2; ++kh)
#pragma unroll
        for (int ni = 0; ni < 2; ++ni)
            pb[kh][ni] = *(const bf16x8*)&Mtb[(size_t)(c0 + ni * 16 + m15) * NTOK + kh * 32 + kq];

#define BIG_ITER(FA, PBC, PBN, IT) do {                                         \
    ushort4 a4;                                                                 \
    a4.x = f2bf(__expf(coef * FA.x));                                           \
    a4.y = f2bf(__expf(coef * FA.y));                                           \
    a4.z = f2bf(__expf(coef * FA.z));                                           \
    a4.w = f2bf(__expf(coef * FA.w));                                           \
    *(ushort4*)&As[swz64(sr, sk)] = a4;                                         \
    __syncthreads();                                                            \
    {   int itA = (IT) + 2;                                                     \
        if (itA < 64) FA = *(const float4*)(arow + itA * 64);                   \
        int itB = (IT) + 1; int kb_ = (itB < 64) ? itB * 64 : 0;                \
        _Pragma("unroll") for (int kh = 0; kh < 2; ++kh)                        \
        _Pragma("unroll") for (int ni = 0; ni < 2; ++ni)                        \
            PBN[kh][ni] = *(const bf16x8*)&Mtb[(size_t)(c0 + ni * 16 + m15) * NTOK + kb_ + kh * 32 + kq]; } \
    _Pragma("unroll") for (int kh = 0; kh < 2; ++kh) {                          \
        bf16x8 a0 = *(const bf16x8*)&As[swz64(m15, kh * 32 + kq)];              \
        bf16x8 a1 = *(const bf16x8*)&As[swz64(16 + m15, kh * 32 + kq)];         \
        acc[0][0] = __builtin_amdgcn_mfma_f32_16x16x32_bf16(a0, PBC[kh][0], acc[0][0], 0, 0, 0); \
        acc[0][1] = __builtin_amdgcn_mfma_f32_16x16x32_bf16(a0, PBC[kh][1], acc[0][1], 0, 0, 0); \
        acc[1][0] = __builtin_amdgcn_mfma_f32_16x16x32_bf16(a1, PBC[kh][0], acc[1][0], 0, 0, 0); \
        acc[1][1] = __builtin_amdgcn_mfma_f32_16x16x32_bf16(a1, PBC[kh][1], acc[1][1], 0, 0, 0); \
    }                                                                           \
    __syncthreads();                                                            \
} while (0)

    for (int it2 = 0; it2 < 32; ++it2) {
        BIG_ITER(fa_e, pb, pbn, it2 * 2);
        BIG_ITER(fa_o, pbn, pb, it2 * 2 + 1);
    }
#undef BIG_ITER

#pragma unroll
    for (int mi = 0; mi < 2; ++mi)
#pragma unroll
        for (int ni = 0; ni < 2; ++ni)
#pragma unroll
            for (int r = 0; r < 4; ++r) {
                int j = j0 + mi * 16 + quad * 4 + r;
                int c = c0 + ni * 16 + m15;
                outp[(size_t)j * 256 + c] = acc[mi][ni][r];
            }
}

// ---------------------------------------------------------------------------
// K3: per-32-row block: attn=sigq*(w1/w2) -> GEMM Wcomb -> +input1 (out1 in
// LDS) -> rms2 (h2 in LDS) -> FFN1/FFN2 in 4 F-chunks -> out = out1+b2+ffn.
// All B operands direct global->reg bf16 (no LDS staging, no stage barriers).
// ---------------------------------------------------------------------------
__launch_bounds__(256, 1)
__global__ void tail_k(const float* __restrict__ sigq, const float* __restrict__ P,
                       const ushort* __restrict__ Wbf,
                       const float* __restrict__ input1, const float* __restrict__ b1,
                       const float* __restrict__ b2, const float* __restrict__ ln2w,
                       float* __restrict__ out) {
    __shared__ ushort As[32 * 128];       // attn A (swizzled), then h2
    __shared__ ushort As2[32 * 128];      // mid chunk (swizzled)
    __shared__ float  O[32][132];         // out1
    const int t = threadIdx.x, lane = t & 63, wv = t >> 6;
    const int m15 = lane & 15, quad = lane >> 4, c0w = wv * 32;
    const int M0 = blockIdx.x * 32;

    // A staging: attn[g,e] = sigq * (P top / P bottom)
    {
        const int ar = t >> 3, e0 = (t & 7) * 16;
        const int g = M0 + ar;
        const float4* sg = (const float4*)(sigq + (size_t)g * 128 + e0);
        const float4* pu = (const float4*)(P + (size_t)g * 256 + e0);
        const float4* pd = (const float4*)(P + (size_t)g * 256 + 128 + e0);
#pragma unroll
        for (int i = 0; i < 4; ++i) {
            float4 s = sg[i], u = pu[i], d = pd[i];
            ushort4 a;
            a.x = f2bf(s.x * u.x / d.x);
            a.y = f2bf(s.y * u.y / d.y);
            a.z = f2bf(s.z * u.z / d.z);
            a.w = f2bf(s.w * u.w / d.w);
            *(ushort4*)&As[swz128(ar, e0 + i * 4)] = a;
        }
    }
    __syncthreads();
    f32x4 acc[2][2] = {};
    gemm_dirB(As, Wbf + 49152, 128, acc, lane, wv);     // x Wcomb^T
    // epilogue 1: out1 = acc + input1 -> LDS O
#pragma unroll
    for (int mi = 0; mi < 2; ++mi)
#pragma unroll
        for (int ni = 0; ni < 2; ++ni)
#pragma unroll
            for (int r = 0; r < 4; ++r) {
                int rl  = mi * 16 + quad * 4 + r;
                int col = c0w + ni * 16 + m15;
                O[rl][col] = acc[mi][ni][r] + input1[(size_t)(M0 + rl) * 128 + col];
            }
    __syncthreads();
    // rms2: h2 = rmsnorm(out1, ln2) -> As (bf16). As reads all done (barrier).
    {
        const int row = t >> 3, seg = t & 7;
        float4 x[4]; float ss = 0.f;
#pragma unroll
        for (int i = 0; i < 4; ++i) {
            x[i] = *(const float4*)&O[row][seg * 16 + i * 4];
            ss += x[i].x * x[i].x + x[i].y * x[i].y + x[i].z * x[i].z + x[i].w * x[i].w;
        }
        ss += __shfl_down(ss, 4, 8);
        ss += __shfl_down(ss, 2, 8);
        ss += __shfl_down(ss, 1, 8);
        ss = __shfl(ss, 0, 8);
        float rr = rsqrtf(ss * (1.0f / 128.0f) + 1e-6f);
#pragma unroll
        for (int i = 0; i < 4; ++i) {
            float4 w4 = *(const float4*)&ln2w[seg * 16 + i * 4];
            ushort4 o;
            o.x = f2bf(x[i].x * rr * w4.x);
            o.y = f2bf(x[i].y * rr * w4.y);
            o.z = f2bf(x[i].z * rr * w4.z);
            o.w = f2bf(x[i].w * rr * w4.w);
            *(ushort4*)&As[swz128(row, seg * 16 + i * 4)] = o;
        }
    }
    // FFN in 4 chunks of F=128
    f32x4 aout[2][2] = {};
    for (int f0 = 0; f0 < 4; ++f0) {
        __syncthreads();   // h2 visible (f0=0); prev chunk's As2 reads done (f0>0)
        f32x4 am[2][2] = {};
        gemm_dirB(As, Wbf + 65536 + f0 * 128 * 128, 128, am, lane, wv);   // x W1 chunk
        // mid = relu(am + b1) -> As2 (bf16)
#pragma unroll
        for (int mi = 0; mi < 2; ++mi)
#pragma unroll
            for (int ni = 0; ni < 2; ++ni)
#pragma unroll
                for (int r = 0; r < 4; ++r) {
                    int rl  = mi * 16 + quad * 4 + r;
                    int col = c0w + ni * 16 + m15;
                    As2[swz128(rl, col)] = f2bf(fmaxf(am[mi][ni][r] + b1[f0 * 128 + col], 0.0f));
                }
        __syncthreads();
        gemm_dirB(As2, Wbf + 131072 + f0 * 128, 512, aout, lane, wv);     // x W2 chunk
    }
    // final: out = out1 + b2 + ffn
#pragma unroll
    for (int mi = 0; mi < 2; ++mi)
#pragma unroll
        for (int ni = 0; ni < 2; ++ni)
#pragma unroll
            for (int r = 0; r < 4; ++r) {
                int rl  = mi * 16 + quad * 4 + r;
                int col = c0w + ni * 16 + m15;
                out[(size_t)(M0 + rl) * 128 + col] = (O[rl][col] + b2[col]) + aout[mi][ni][r];
            }
}

// ---------------------------------------------------------------------------
extern "C" void kernel_launch(void* const* d_in, const int* in_sizes, int n_in,
                              void* d_out, int out_size, void* d_ws, size_t ws_size,
                              hipStream_t stream) {
    const float* input1 = (const float*)d_in[0];
    const float* dis    = (const float*)d_in[1];
    const float* Wq     = (const float*)d_in[2];
    const float* Wk     = (const float*)d_in[3];
    const float* Wv     = (const float*)d_in[4];
    const float* alpha  = (const float*)d_in[5];
    const float* ln1    = (const float*)d_in[6];
    const float* ln2    = (const float*)d_in[7];
    const float* Wcomb  = (const float*)d_in[8];
    const float* W1     = (const float*)d_in[9];
    const float* b1     = (const float*)d_in[10];
    const float* W2     = (const float*)d_in[11];
    const float* b2     = (const float*)d_in[12];
    float* out = (float*)d_out;

    // workspace overlay (peak 20 MiB)
    char* w8 = (char*)d_ws;
    ushort* Wbf  = (ushort*)(w8);                  // [0,384K)  Wcomb/W1/W2 bf16
    float*  sigq = (float*)(w8 + (4u << 20));      // [4,8M)
    ushort* Mt   = (ushort*)(w8 + (8u << 20));     // [8,12M)
    float*  P    = (float*)(w8 + (12u << 20));     // [12,20M)

    // 1) fused rms1 + Q/K/V (+ weight conversion for tail)
    qkv_k<<<dim3(400), 256, 0, stream>>>(input1, ln1, Wq, Wk, Wv,
                                         Wcomb, W1, W2, Wbf, sigq, Mt);
    // 2) big GEMM, K-full, 32j-tiles, B direct-to-reg, swizzled A-LDS
    big_gemm_k<<<dim3(256), 512, 0, stream>>>(dis, alpha, Mt, P);
    // 3) attn + Wcomb + residual + rms2 + FFN1 + FFN2 -> out
    tail_k<<<dim3(256), 256, 0, stream>>>(sigq, P, Wbf, input1, b1, b2, ln2, out);
}

// Round 4
// 258.344 us; speedup vs baseline: 1.1099x; 1.1099x over previous
//
#include <hip/hip_runtime.h>

#define NTOK 4096          // N
#define EDIM 128

typedef __attribute__((ext_vector_type(8))) short bf16x8;
typedef __attribute__((ext_vector_type(4))) float f32x4;

__device__ __forceinline__ ushort f2bf(float x) {
    union { float f; unsigned u; } c; c.f = x;
    unsigned r = c.u + 0x7FFF + ((c.u >> 16) & 1);
    return (ushort)(r >> 16);
}

// XOR-swizzled LDS index helpers (ushort units). k ^= (row&7)<<3 spreads the
// 16-B chunks of 8 consecutive rows across banks; preserves 16-B alignment.
__device__ __forceinline__ int swz64(int r, int k)  { return r * 64  + (k ^ ((r & 7) << 3)); }
__device__ __forceinline__ int swz128(int r, int k) { return r * 128 + (k ^ ((r & 7) << 3)); }

// stage a 128x128 fp32 weight (row-major) into bf16 LDS tile [128][136]
__device__ __forceinline__ void stage_w(const float* __restrict__ W, ushort* Bs) {
    const int t = threadIdx.x;
    const int br = t >> 1, h = (t & 1) * 64;
    const float* src = W + (size_t)br * 128 + h;
    ushort* dst = Bs + br * 136 + h;
#pragma unroll
    for (int j = 0; j < 8; ++j) {
        float4 u = *(const float4*)(src + j * 8);
        float4 v = *(const float4*)(src + j * 8 + 4);
        bf16x8 o;
        o[0] = (short)f2bf(u.x); o[1] = (short)f2bf(u.y);
        o[2] = (short)f2bf(u.z); o[3] = (short)f2bf(u.w);
        o[4] = (short)f2bf(v.x); o[5] = (short)f2bf(v.y);
        o[6] = (short)f2bf(v.z); o[7] = (short)f2bf(v.w);
        *(bf16x8*)(dst + j * 8) = o;
    }
}

// 32x128 x K=128 bf16 MFMA GEMM from LDS tiles (As[32][136], Bs[128][136])
__device__ __forceinline__ void gemm128(const ushort* __restrict__ As,
                                        const ushort* __restrict__ Bs,
                                        f32x4 (&acc)[2][2], int lane, int wv) {
    const int m15 = lane & 15, kq = (lane >> 4) * 8, c0w = wv * 32;
#pragma unroll
    for (int kc = 0; kc < 4; ++kc) {
        int ko = kc * 32 + kq;
        bf16x8 a0 = *(const bf16x8*)&As[m15 * 136 + ko];
        bf16x8 a1 = *(const bf16x8*)&As[(16 + m15) * 136 + ko];
        bf16x8 b0 = *(const bf16x8*)&Bs[(c0w + m15) * 136 + ko];
        bf16x8 b1 = *(const bf16x8*)&Bs[(c0w + 16 + m15) * 136 + ko];
        acc[0][0] = __builtin_amdgcn_mfma_f32_16x16x32_bf16(a0, b0, acc[0][0], 0, 0, 0);
        acc[0][1] = __builtin_amdgcn_mfma_f32_16x16x32_bf16(a0, b1, acc[0][1], 0, 0, 0);
        acc[1][0] = __builtin_amdgcn_mfma_f32_16x16x32_bf16(a1, b0, acc[1][0], 0, 0, 0);
        acc[1][1] = __builtin_amdgcn_mfma_f32_16x16x32_bf16(a1, b1, acc[1][1], 0, 0, 0);
    }
}

// 32x128 GEMM: A from swizzled LDS [32][128], B bf16 fragments DIRECT from
// global (per-wave-private rows -> no LDS staging, no barriers).
__device__ __forceinline__ void gemm_dirB(const ushort* __restrict__ As,
                                          const ushort* __restrict__ W, int ldb,
                                          f32x4 (&acc)[2][2], int lane, int wv) {
    const int m15 = lane & 15, kq = (lane >> 4) * 8, c0w = wv * 32;
#pragma unroll
    for (int kc = 0; kc < 4; ++kc) {
        int ko = kc * 32 + kq;
        bf16x8 a0 = *(const bf16x8*)&As[swz128(m15, ko)];
        bf16x8 a1 = *(const bf16x8*)&As[swz128(16 + m15, ko)];
        bf16x8 b0 = *(const bf16x8*)&W[(size_t)(c0w + m15) * ldb + ko];
        bf16x8 b1 = *(const bf16x8*)&W[(size_t)(c0w + 16 + m15) * ldb + ko];
        acc[0][0] = __builtin_amdgcn_mfma_f32_16x16x32_bf16(a0, b0, acc[0][0], 0, 0, 0);
        acc[0][1] = __builtin_amdgcn_mfma_f32_16x16x32_bf16(a0, b1, acc[0][1], 0, 0, 0);
        acc[1][0] = __builtin_amdgcn_mfma_f32_16x16x32_bf16(a1, b0, acc[1][0], 0, 0, 0);
        acc[1][1] = __builtin_amdgcn_mfma_f32_16x16x32_bf16(a1, b1, acc[1][1], 0, 0, 0);
    }
}

// ---------------------------------------------------------------------------
// K1: blocks [0,256): per-32-row fused rms1 + Q/K/V GEMMs -> sigq, Mt.
//     blocks [256,400): Wcomb/W1/W2 fp32->bf16 for the tail kernel.
// ---------------------------------------------------------------------------
__launch_bounds__(256, 2)
__global__ void qkv_k(const float* __restrict__ input1, const float* __restrict__ ln1w,
                      const float* __restrict__ Wq, const float* __restrict__ Wk,
                      const float* __restrict__ Wv,
                      const float* __restrict__ Wc, const float* __restrict__ W1,
                      const float* __restrict__ W2, ushort* __restrict__ Wbf,
                      float* __restrict__ sigq, ushort* __restrict__ Mt) {
    const int bx = blockIdx.x;
    if (bx >= 256) {                       // weight conversion (147456 f32)
        int g = ((bx - 256) * 256 + threadIdx.x) * 4;
        const float* src; ushort* dst;
        if (g < 16384)      { src = Wc + g;           dst = Wbf + 49152 + g; }
        else if (g < 81920) { src = W1 + (g - 16384); dst = Wbf + 65536 + (g - 16384); }
        else                { src = W2 + (g - 81920); dst = Wbf + 131072 + (g - 81920); }
        float4 u = *(const float4*)src;
        ushort4 o; o.x = f2bf(u.x); o.y = f2bf(u.y); o.z = f2bf(u.z); o.w = f2bf(u.w);
        *(ushort4*)dst = o;
        return;
    }
    __shared__ ushort As[32 * 136];
    __shared__ ushort Bs0[128 * 136];
    __shared__ ushort Bs1[128 * 136];
    const int t = threadIdx.x, lane = t & 63, wv = t >> 6;
    const int m15 = lane & 15, quad = lane >> 4, c0w = wv * 32;
    const int M0 = bx * 32;

    // rms1: h = rmsnorm(input1 rows, ln1) -> As (bf16)
    {
        const int row = t >> 3, seg = t & 7;
        const float* xp = input1 + (size_t)(M0 + row) * 128 + seg * 16;
        float4 x[4]; float ss = 0.f;
#pragma unroll
        for (int i = 0; i < 4; ++i) {
            x[i] = *(const float4*)(xp + i * 4);
            ss += x[i].x * x[i].x + x[i].y * x[i].y + x[i].z * x[i].z + x[i].w * x[i].w;
        }
        ss += __shfl_down(ss, 4, 8);
        ss += __shfl_down(ss, 2, 8);
        ss += __shfl_down(ss, 1, 8);
        ss = __shfl(ss, 0, 8);
        float rr = rsqrtf(ss * (1.0f / 128.0f) + 1e-6f);
#pragma unroll
        for (int i = 0; i < 4; ++i) {
            float4 w4 = *(const float4*)&ln1w[seg * 16 + i * 4];
            ushort4 o;
            o.x = f2bf(x[i].x * rr * w4.x);
            o.y = f2bf(x[i].y * rr * w4.y);
            o.z = f2bf(x[i].z * rr * w4.z);
            o.w = f2bf(x[i].w * rr * w4.w);
            *(ushort4*)&As[row * 136 + seg * 16 + i * 4] = o;
        }
    }
    stage_w(Wq, Bs0);
    __syncthreads();
    {   // GEMM q -> sigmoid -> sigq ; overlap Wk staging into Bs1
        f32x4 acc[2][2] = {};
        gemm128(As, Bs0, acc, lane, wv);
        stage_w(Wk, Bs1);
#pragma unroll
        for (int mi = 0; mi < 2; ++mi)
#pragma unroll
            for (int ni = 0; ni < 2; ++ni)
#pragma unroll
                for (int r = 0; r < 4; ++r) {
                    int row = M0 + mi * 16 + quad * 4 + r;
                    int lc  = c0w + ni * 16 + m15;
                    sigq[(size_t)row * 128 + lc] = 1.0f / (1.0f + __expf(-acc[mi][ni][r]));
                }
    }
    __syncthreads();
    f32x4 acck[2][2] = {};
    gemm128(As, Bs1, acck, lane, wv);
    stage_w(Wv, Bs0);                     // Bs0 free: all q-reads done at last barrier
    __syncthreads();
    f32x4 accv[2][2] = {};
    gemm128(As, Bs0, accv, lane, wv);
    // Mt epilogue: Mt[b][e][i]=exp(k)*v, Mt[b][128+e][i]=exp(k)
    const int b = M0 >> 12, i0 = M0 & (NTOK - 1);
#pragma unroll
    for (int mi = 0; mi < 2; ++mi)
#pragma unroll
        for (int ni = 0; ni < 2; ++ni) {
            int e = c0w + ni * 16 + m15;
            ushort* mt0 = Mt + ((size_t)b * 256 + e) * NTOK;
            ushort* mt1 = mt0 + (size_t)128 * NTOK;
            int ib = i0 + mi * 16 + quad * 4;
            ushort4 pv, pk;
            float kw0 = __expf(acck[mi][ni][0]); pv.x = f2bf(kw0 * accv[mi][ni][0]); pk.x = f2bf(kw0);
            float kw1 = __expf(acck[mi][ni][1]); pv.y = f2bf(kw1 * accv[mi][ni][1]); pk.y = f2bf(kw1);
            float kw2 = __expf(acck[mi][ni][2]); pv.z = f2bf(kw2 * accv[mi][ni][2]); pk.z = f2bf(kw2);
            float kw3 = __expf(acck[mi][ni][3]); pv.w = f2bf(kw3 * accv[mi][ni][3]); pk.w = f2bf(kw3);
            *(ushort4*)&mt0[ib] = pv;
            *(ushort4*)&mt1[ib] = pk;
        }
}

// ---------------------------------------------------------------------------
// K2: P[b,j,c] = sum_i exp(coef*dis[b,j,i]) * Mt[b,c,i]
// 64j x 256c tile, BK=64, K-split 2 -> grid 256 (64 jt x 2 b x 2 s).
// 512 thr, 8 waves, each 64j x 32c (acc[4][2], 16 MFMA/iter). A exp'd into
// XOR-swizzled DOUBLE-BUFFERED LDS -> ONE barrier/iter, and the barrier is a
// raw lgkmcnt(0)+s_barrier (no vmcnt drain -> prefetches stay in flight).
// A prefetch depth 2, B (Mt, direct->reg) depth 1; load issue pinned with
// sched_barrier(0) so the compiler can't sink them (round-2 failure mode).
// b = blockIdx&1 keeps each 2 MB Mt panel on one XCD parity.
// ---------------------------------------------------------------------------
__launch_bounds__(512, 2)
__global__ void big_gemm_k(const float* __restrict__ dis, const float* __restrict__ alphap,
                           const ushort* __restrict__ Mt,
                           float* __restrict__ P0, float* __restrict__ P1) {
    __shared__ ushort As[2][64 * 64];
    const int t = threadIdx.x, lane = t & 63, wv = t >> 6;
    const int m15 = lane & 15, quad = lane >> 4, kq = quad * 8;
    const int b  = blockIdx.x & 1;
    const int s  = (blockIdx.x >> 1) & 1;
    const int j0 = (blockIdx.x >> 2) * 64;
    const float coefl2 = -alphap[0] * 12.0f * 1.44269504088896f; // fold log2e
    const float* disb = dis + (size_t)b * NTOK * NTOK;
    const ushort* Mtb = Mt + (size_t)b * 256 * NTOK;
    float* outp = ((s == 0) ? P0 : P1) + (size_t)b * NTOK * 256;
    const int k0 = s * (NTOK / 2);

    const int sr = t >> 3, sk = (t & 7) * 8;    // A stage: 64 rows x 8 floats/thr
    const float* arow = disb + (size_t)(j0 + sr) * NTOK + k0 + sk;
    const int c0 = wv * 32;
    const ushort* Bp = Mtb + (size_t)(c0 + m15) * NTOK + k0 + kq;
    const ushort* Bp1 = Bp + (size_t)16 * NTOK;

    f32x4 acc[4][2] = {};
    float4 fa0, fa1, fb0, fb1;                  // A prefetch (depth 2)
    bf16x8 pb[2][2], pbn[2][2];                 // B prefetch (depth 1)

    {   // prologue: stage iter 0 into As[0]; preload A(1), B(0)
        float4 g0 = *(const float4*)(arow);
        float4 g1 = *(const float4*)(arow + 4);
        bf16x8 a8;
        a8[0] = (short)f2bf(exp2f(coefl2 * g0.x));
        a8[1] = (short)f2bf(exp2f(coefl2 * g0.y));
        a8[2] = (short)f2bf(exp2f(coefl2 * g0.z));
        a8[3] = (short)f2bf(exp2f(coefl2 * g0.w));
        a8[4] = (short)f2bf(exp2f(coefl2 * g1.x));
        a8[5] = (short)f2bf(exp2f(coefl2 * g1.y));
        a8[6] = (short)f2bf(exp2f(coefl2 * g1.z));
        a8[7] = (short)f2bf(exp2f(coefl2 * g1.w));
        *(bf16x8*)&As[0][swz64(sr, sk)] = a8;
        fa0 = *(const float4*)(arow + 64);
        fa1 = *(const float4*)(arow + 68);
#pragma unroll
        for (int kh = 0; kh < 2; ++kh) {
            pb[kh][0] = *(const bf16x8*)&Bp[kh * 32];
            pb[kh][1] = *(const bf16x8*)&Bp1[kh * 32];
        }
        __syncthreads();
    }

    // FAc: A data for IT+1 (held in regs); FAn: issue A for IT+2.
    // PBC: B data for IT (consumed by MFMA); PBN: issue B for IT+1.
    // BUFC = As[IT&1] (A for IT); write exp(FAc) into BUFN = As[(IT+1)&1].
#define BIG_ITER(FAc0, FAc1, FAn0, FAn1, PBC, PBN, BUFC, BUFN, IT) do {         \
    {   int ia = (IT) + 2; int ka = (ia < 32) ? ia * 64 : 0;                    \
        FAn0 = *(const float4*)(arow + ka);                                     \
        FAn1 = *(const float4*)(arow + ka + 4);                                 \
        int ib = (IT) + 1; int kb_ = (ib < 32) ? ib * 64 : 0;                   \
        _Pragma("unroll") for (int kh = 0; kh < 2; ++kh) {                      \
            PBN[kh][0] = *(const bf16x8*)&Bp[kb_ + kh * 32];                    \
            PBN[kh][1] = *(const bf16x8*)&Bp1[kb_ + kh * 32];                   \
        } }                                                                     \
    __builtin_amdgcn_sched_barrier(0);                                          \
    {   bf16x8 a8;                                                              \
        a8[0] = (short)f2bf(exp2f(coefl2 * FAc0.x));                            \
        a8[1] = (short)f2bf(exp2f(coefl2 * FAc0.y));                            \
        a8[2] = (short)f2bf(exp2f(coefl2 * FAc0.z));                            \
        a8[3] = (short)f2bf(exp2f(coefl2 * FAc0.w));                            \
        a8[4] = (short)f2bf(exp2f(coefl2 * FAc1.x));                            \
        a8[5] = (short)f2bf(exp2f(coefl2 * FAc1.y));                            \
        a8[6] = (short)f2bf(exp2f(coefl2 * FAc1.z));                            \
        a8[7] = (short)f2bf(exp2f(coefl2 * FAc1.w));                            \
        *(bf16x8*)&BUFN[swz64(sr, sk)] = a8; }                                  \
    _Pragma("unroll") for (int kh = 0; kh < 2; ++kh) {                          \
        bf16x8 a0 = *(const bf16x8*)&BUFC[swz64(m15,      kh * 32 + kq)];       \
        bf16x8 a1 = *(const bf16x8*)&BUFC[swz64(16 + m15, kh * 32 + kq)];       \
        bf16x8 a2 = *(const bf16x8*)&BUFC[swz64(32 + m15, kh * 32 + kq)];       \
        bf16x8 a3 = *(const bf16x8*)&BUFC[swz64(48 + m15, kh * 32 + kq)];       \
        acc[0][0] = __builtin_amdgcn_mfma_f32_16x16x32_bf16(a0, PBC[kh][0], acc[0][0], 0, 0, 0); \
        acc[0][1] = __builtin_amdgcn_mfma_f32_16x16x32_bf16(a0, PBC[kh][1], acc[0][1], 0, 0, 0); \
        acc[1][0] = __builtin_amdgcn_mfma_f32_16x16x32_bf16(a1, PBC[kh][0], acc[1][0], 0, 0, 0); \
        acc[1][1] = __builtin_amdgcn_mfma_f32_16x16x32_bf16(a1, PBC[kh][1], acc[1][1], 0, 0, 0); \
        acc[2][0] = __builtin_amdgcn_mfma_f32_16x16x32_bf16(a2, PBC[kh][0], acc[2][0], 0, 0, 0); \
        acc[2][1] = __builtin_amdgcn_mfma_f32_16x16x32_bf16(a2, PBC[kh][1], acc[2][1], 0, 0, 0); \
        acc[3][0] = __builtin_amdgcn_mfma_f32_16x16x32_bf16(a3, PBC[kh][0], acc[3][0], 0, 0, 0); \
        acc[3][1] = __builtin_amdgcn_mfma_f32_16x16x32_bf16(a3, PBC[kh][1], acc[3][1], 0, 0, 0); \
    }                                                                           \
    __builtin_amdgcn_sched_barrier(0);                                          \
    asm volatile("s_waitcnt lgkmcnt(0)" ::: "memory");                          \
    __builtin_amdgcn_s_barrier();                                               \
    __builtin_amdgcn_sched_barrier(0);                                          \
} while (0)

#pragma unroll 1
    for (int u = 0; u < 16; ++u) {
        int IT = u * 2;
        BIG_ITER(fa0, fa1, fb0, fb1, pb, pbn, As[0], As[1], IT);
        BIG_ITER(fb0, fb1, fa0, fa1, pbn, pb, As[1], As[0], IT + 1);
    }
#undef BIG_ITER

#pragma unroll
    for (int mi = 0; mi < 4; ++mi)
#pragma unroll
        for (int ni = 0; ni < 2; ++ni)
#pragma unroll
            for (int r = 0; r < 4; ++r) {
                int j = j0 + mi * 16 + quad * 4 + r;
                int c = c0 + ni * 16 + m15;
                outp[(size_t)j * 256 + c] = acc[mi][ni][r];
            }
}

// ---------------------------------------------------------------------------
// K3: per-32-row block: attn=sigq*(w1/w2) -> GEMM Wcomb -> +input1 (out1 in
// LDS) -> rms2 (h2 in LDS) -> FFN1/FFN2 in 4 F-chunks -> out = out1+b2+ffn.
// All B operands direct global->reg bf16 (no LDS staging, no stage barriers).
// ---------------------------------------------------------------------------
__launch_bounds__(256, 1)
__global__ void tail_k(const float* __restrict__ sigq,
                       const float* __restrict__ P0, const float* __restrict__ P1,
                       const ushort* __restrict__ Wbf,
                       const float* __restrict__ input1, const float* __restrict__ b1,
                       const float* __restrict__ b2, const float* __restrict__ ln2w,
                       float* __restrict__ out) {
    __shared__ ushort As[32 * 128];       // attn A (swizzled), then h2
    __shared__ ushort As2[32 * 128];      // mid chunk (swizzled)
    __shared__ float  O[32][132];         // out1
    const int t = threadIdx.x, lane = t & 63, wv = t >> 6;
    const int m15 = lane & 15, quad = lane >> 4, c0w = wv * 32;
    const int M0 = blockIdx.x * 32;

    // A staging: attn[g,e] = sigq * (P0+P1 top)/(P0+P1 bottom)
    {
        const int ar = t >> 3, e0 = (t & 7) * 16;
        const int g = M0 + ar;
        const float4* sg  = (const float4*)(sigq + (size_t)g * 128 + e0);
        const float4* p0a = (const float4*)(P0 + (size_t)g * 256 + e0);
        const float4* p1a = (const float4*)(P1 + (size_t)g * 256 + e0);
        const float4* p0b = (const float4*)(P0 + (size_t)g * 256 + 128 + e0);
        const float4* p1b = (const float4*)(P1 + (size_t)g * 256 + 128 + e0);
#pragma unroll
        for (int i = 0; i < 4; ++i) {
            float4 s = sg[i];
            float4 u0 = p0a[i], u1 = p1a[i], d0 = p0b[i], d1 = p1b[i];
            ushort4 a;
            a.x = f2bf(s.x * (u0.x + u1.x) / (d0.x + d1.x));
            a.y = f2bf(s.y * (u0.y + u1.y) / (d0.y + d1.y));
            a.z = f2bf(s.z * (u0.z + u1.z) / (d0.z + d1.z));
            a.w = f2bf(s.w * (u0.w + u1.w) / (d0.w + d1.w));
            *(ushort4*)&As[swz128(ar, e0 + i * 4)] = a;
        }
    }
    __syncthreads();
    f32x4 acc[2][2] = {};
    gemm_dirB(As, Wbf + 49152, 128, acc, lane, wv);     // x Wcomb^T
    // epilogue 1: out1 = acc + input1 -> LDS O
#pragma unroll
    for (int mi = 0; mi < 2; ++mi)
#pragma unroll
        for (int ni = 0; ni < 2; ++ni)
#pragma unroll
            for (int r = 0; r < 4; ++r) {
                int rl  = mi * 16 + quad * 4 + r;
                int col = c0w + ni * 16 + m15;
                O[rl][col] = acc[mi][ni][r] + input1[(size_t)(M0 + rl) * 128 + col];
            }
    __syncthreads();
    // rms2: h2 = rmsnorm(out1, ln2) -> As (bf16). As reads all done (barrier).
    {
        const int row = t >> 3, seg = t & 7;
        float4 x[4]; float ss = 0.f;
#pragma unroll
        for (int i = 0; i < 4; ++i) {
            x[i] = *(const float4*)&O[row][seg * 16 + i * 4];
            ss += x[i].x * x[i].x + x[i].y * x[i].y + x[i].z * x[i].z + x[i].w * x[i].w;
        }
        ss += __shfl_down(ss, 4, 8);
        ss += __shfl_down(ss, 2, 8);
        ss += __shfl_down(ss, 1, 8);
        ss = __shfl(ss, 0, 8);
        float rr = rsqrtf(ss * (1.0f / 128.0f) + 1e-6f);
#pragma unroll
        for (int i = 0; i < 4; ++i) {
            float4 w4 = *(const float4*)&ln2w[seg * 16 + i * 4];
            ushort4 o;
            o.x = f2bf(x[i].x * rr * w4.x);
            o.y = f2bf(x[i].y * rr * w4.y);
            o.z = f2bf(x[i].z * rr * w4.z);
            o.w = f2bf(x[i].w * rr * w4.w);
            *(ushort4*)&As[swz128(row, seg * 16 + i * 4)] = o;
        }
    }
    // FFN in 4 chunks of F=128
    f32x4 aout[2][2] = {};
    for (int f0 = 0; f0 < 4; ++f0) {
        __syncthreads();   // h2 visible (f0=0); prev chunk's As2 reads done (f0>0)
        f32x4 am[2][2] = {};
        gemm_dirB(As, Wbf + 65536 + f0 * 128 * 128, 128, am, lane, wv);   // x W1 chunk
        // mid = relu(am + b1) -> As2 (bf16)
#pragma unroll
        for (int mi = 0; mi < 2; ++mi)
#pragma unroll
            for (int ni = 0; ni < 2; ++ni)
#pragma unroll
                for (int r = 0; r < 4; ++r) {
                    int rl  = mi * 16 + quad * 4 + r;
                    int col = c0w + ni * 16 + m15;
                    As2[swz128(rl, col)] = f2bf(fmaxf(am[mi][ni][r] + b1[f0 * 128 + col], 0.0f));
                }
        __syncthreads();
        gemm_dirB(As2, Wbf + 131072 + f0 * 128, 512, aout, lane, wv);     // x W2 chunk
    }
    // final: out = out1 + b2 + ffn
#pragma unroll
    for (int mi = 0; mi < 2; ++mi)
#pragma unroll
        for (int ni = 0; ni < 2; ++ni)
#pragma unroll
            for (int r = 0; r < 4; ++r) {
                int rl  = mi * 16 + quad * 4 + r;
                int col = c0w + ni * 16 + m15;
                out[(size_t)(M0 + rl) * 128 + col] = (O[rl][col] + b2[col]) + aout[mi][ni][r];
            }
}

// ---------------------------------------------------------------------------
extern "C" void kernel_launch(void* const* d_in, const int* in_sizes, int n_in,
                              void* d_out, int out_size, void* d_ws, size_t ws_size,
                              hipStream_t stream) {
    const float* input1 = (const float*)d_in[0];
    const float* dis    = (const float*)d_in[1];
    const float* Wq     = (const float*)d_in[2];
    const float* Wk     = (const float*)d_in[3];
    const float* Wv     = (const float*)d_in[4];
    const float* alpha  = (const float*)d_in[5];
    const float* ln1    = (const float*)d_in[6];
    const float* ln2    = (const float*)d_in[7];
    const float* Wcomb  = (const float*)d_in[8];
    const float* W1     = (const float*)d_in[9];
    const float* b1     = (const float*)d_in[10];
    const float* W2     = (const float*)d_in[11];
    const float* b2     = (const float*)d_in[12];
    float* out = (float*)d_out;

    // workspace overlay (peak 28 MiB)
    char* w8 = (char*)d_ws;
    ushort* Wbf  = (ushort*)(w8);                  // [0,384K)  Wcomb/W1/W2 bf16
    float*  sigq = (float*)(w8 + (4u << 20));      // [4,8M)
    ushort* Mt   = (ushort*)(w8 + (8u << 20));     // [8,12M)
    float*  P0   = (float*)(w8 + (12u << 20));     // [12,20M)
    float*  P1   = (float*)(w8 + (20u << 20));     // [20,28M)

    // 1) fused rms1 + Q/K/V (+ weight conversion for tail)
    qkv_k<<<dim3(400), 256, 0, stream>>>(input1, ln1, Wq, Wk, Wv,
                                         Wcomb, W1, W2, Wbf, sigq, Mt);
    // 2) big GEMM, 64j x 256c, K-split 2, dbuf LDS, raw counted-wait barrier
    big_gemm_k<<<dim3(256), 512, 0, stream>>>(dis, alpha, Mt, P0, P1);
    // 3) attn + Wcomb + residual + rms2 + FFN1 + FFN2 -> out
    tail_k<<<dim3(256), 256, 0, stream>>>(sigq, P0, P1, Wbf, input1, b1, b2,
                                          ln2, out);
}